// Round 11
// baseline (875.340 us; speedup 1.0000x reference)
//
#include <hip/hip_runtime.h>

#define NN 30000
#define NE 600000
#define RR 32
#define NBASE 30
#define NG 16

typedef long long i64;
typedef unsigned short ushort;
typedef short bf16x8 __attribute__((ext_vector_type(8)));
typedef float f32x4 __attribute__((ext_vector_type(4)));

__device__ __forceinline__ ushort f2bf(float f){
  unsigned u = __float_as_uint(f);
  u += 0x7fffu + ((u >> 16) & 1u);   // RNE
  return (ushort)(u >> 16);
}
__device__ __forceinline__ float bf2f(ushort u){
  return __uint_as_float(((unsigned)u) << 16);
}
__device__ __forceinline__ unsigned pk2(float a, float b){
  return (unsigned)f2bf(a) | ((unsigned)f2bf(b) << 16);
}

// x[n] = entity_emb[node_ids[n]] (fp32 + bf16 shadow) + per-graph node count
__global__ __launch_bounds__(256) void k_gather(const float* __restrict__ emb,
    const int* __restrict__ ids, const int* __restrict__ batch,
    float* __restrict__ x, ushort* __restrict__ xb, float* __restrict__ cntg){
  __shared__ int lh[NG];
  if (threadIdx.x < NG) lh[threadIdx.x] = 0;
  __syncthreads();
  int t = blockIdx.x*256 + threadIdx.x;       // grid 3750*256 == NN*32 exact
  int n = t >> 5, c = t & 31;
  float4 v = ((const float4*)emb)[(i64)ids[n]*32 + c];
  ((float4*)x)[(i64)n*32 + c] = v;
  *(uint2*)&xb[(i64)n*128 + c*4] = make_uint2(pk2(v.x, v.y), pk2(v.z, v.w));
  if (c == 0) atomicAdd(&lh[batch[n]], 1);
  __syncthreads();
  if (threadIdx.x < NG){
    int cv = lh[threadIdx.x];
    if (cv) atomicAdd(&cntg[threadIdx.x], (float)cv);
  }
}

// one pass over edges: relation hist (LDS-agg), target hist, (tgt,rel) counts
__global__ __launch_bounds__(256) void k_stats(const int* __restrict__ etgt,
    const int* __restrict__ ety, float* __restrict__ cnt,
    int* __restrict__ hist, int* __restrict__ hist2){
  __shared__ int lh[RR];
  if (threadIdx.x < RR) lh[threadIdx.x] = 0;
  __syncthreads();
  int e0 = blockIdx.x*2048 + threadIdx.x;
  #pragma unroll
  for (int i = 0; i < 8; i++){
    int e = e0 + i*256;
    if (e < NE){
      int tgt = etgt[e], r = ety[e];
      atomicAdd(&lh[r], 1);
      atomicAdd(&hist2[tgt], 1);
      atomicAdd(&cnt[(i64)tgt*RR + r], 1.0f);
    }
  }
  __syncthreads();
  if (threadIdx.x < RR){
    int v = lh[threadIdx.x];
    if (v) atomicAdd(&hist[threadIdx.x], v);
  }
}

// CSR scan over targets + (thread 0) relation scan
__global__ __launch_bounds__(1024) void k_scan2(const int* __restrict__ hist2,
    int* __restrict__ rowptr, int* __restrict__ cursor2,
    const int* __restrict__ hist, int* __restrict__ base,
    int* __restrict__ cursor, int* __restrict__ pb, int* __restrict__ pb64){
  int t = threadIdx.x;
  if (t == 0){
    int s = 0, p = 0, p64 = 0;
    for (int r = 0; r < RR; r++){
      base[r] = s; cursor[r] = s; pb[r] = p; pb64[r] = p64;
      s += hist[r]; p += (hist[r] + 127) >> 7; p64 += (hist[r] + 63) >> 6;
    }
    base[RR] = s; pb[RR] = p; pb64[RR] = p64;
  }
  __shared__ int s[1024];
  int bse = t*30;
  int loc[30];
  int sum = 0;
  #pragma unroll
  for (int i = 0; i < 30; i++){
    int v = (bse+i < NN) ? hist2[bse+i] : 0;
    loc[i] = sum; sum += v;
  }
  s[t] = sum; __syncthreads();
  for (int off = 1; off < 1024; off <<= 1){
    int v = (t >= off) ? s[t-off] : 0;
    __syncthreads();
    s[t] += v;
    __syncthreads();
  }
  int excl = (t > 0) ? s[t-1] : 0;
  #pragma unroll
  for (int i = 0; i < 30; i++){
    int idx = bse + i;
    if (idx <= NN){
      rowptr[idx] = excl + loc[i];
      if (idx < NN) cursor2[idx] = excl + loc[i];
    }
  }
}

// se2[q] = (src, rel) in CSR order; pos2: edge -> csr slot; 8 pad entries
__global__ void k_scatter2(const int* __restrict__ etgt, const int* __restrict__ esrc,
                           const int* __restrict__ ety, int* __restrict__ cursor2,
                           int2* __restrict__ se2, int* __restrict__ pos2){
  int e = blockIdx.x*256 + threadIdx.x;
  if (e >= NE) return;
  int q = atomicAdd(&cursor2[etgt[e]], 1);
  se2[q] = make_int2(esrc[e], ety[e]);
  pos2[e] = q;
  if (e < 8) se2[NE + e] = make_int2(0, 0);
}

// block-aggregated relation scatter; fused per-slot metadata (src, csr-slot, 1/cnt)
__global__ __launch_bounds__(256) void k_scatter_blk(const int* __restrict__ ety,
    const int* __restrict__ esrc, const int* __restrict__ etgt,
    const int* __restrict__ pos2, const float* __restrict__ cnt,
    int* __restrict__ cursor, int* __restrict__ eord,
    int* __restrict__ sg_src, int* __restrict__ sg_p2, float* __restrict__ sg_inv){
  __shared__ int lh[RR];
  __shared__ int lb[RR];
  if (threadIdx.x < RR) lh[threadIdx.x] = 0;
  __syncthreads();
  int e0 = blockIdx.x*2048 + threadIdx.x;
  #pragma unroll
  for (int i = 0; i < 8; i++){
    int e = e0 + i*256;
    if (e < NE) atomicAdd(&lh[ety[e]], 1);
  }
  __syncthreads();
  if (threadIdx.x < RR){
    int c = lh[threadIdx.x];
    lb[threadIdx.x] = c ? atomicAdd(&cursor[threadIdx.x], c) : 0;
  }
  __syncthreads();
  if (threadIdx.x < RR) lh[threadIdx.x] = 0;
  __syncthreads();
  #pragma unroll
  for (int i = 0; i < 8; i++){
    int e = e0 + i*256;
    if (e < NE){
      int r = ety[e];
      int loc = atomicAdd(&lh[r], 1);
      int slot = lb[r] + loc;
      eord[slot]   = e;
      sg_src[slot] = esrc[e];
      sg_p2[slot]  = pos2[e];
      sg_inv[slot] = 1.0f / cnt[(i64)etgt[e]*RR + r];
    }
  }
}

// both layers: wbT[l][r][c][k] = sum_b comp[l][r][b]*bases[l][b][k][c]
__global__ void k_basis(const float* __restrict__ comp, const float* __restrict__ bases,
                        float* __restrict__ wT, ushort* __restrict__ wTb){
  int t = blockIdx.x*256 + threadIdx.x;     // 4096 blocks = 2*RR*16384
  int lyr = t >> 19;
  int rem = t & 524287;
  int r = rem >> 14, rem2 = rem & 16383, c = rem2 >> 7, kk = rem2 & 127;
  const float* cp = comp + (i64)lyr*RR*NBASE + r*NBASE;
  const float* bs = bases + (i64)lyr*NBASE*16384;
  float acc = 0.f;
  for (int b = 0; b < NBASE; b++)
    acc += cp[b] * bs[(i64)b*16384 + kk*128 + c];
  wT[t] = acc;
  wTb[t] = f2bf(acc);
}

// transpose dense weights -> bf16 [out][in]
__global__ void k_tw(const float* __restrict__ root, const float* __restrict__ wq,
                     const float* __restrict__ wk, const float* __restrict__ wv,
                     const float* __restrict__ wsk, ushort* __restrict__ out){
  int z = blockIdx.y;
  const float* srcs[5] = {root, wq, wk, wv, wsk};
  const float* S = srcs[z >> 1] + (i64)(z & 1)*16384;
  int idx = blockIdx.x*256 + threadIdx.x;
  int c = idx >> 7, kk = idx & 127;
  out[(i64)z*16384 + idx] = f2bf(S[kk*128 + c]);
}

// both layers: ew[l][r][c] = rel_emb[r] @ We[l]
__global__ void k_ew(const float* __restrict__ rel, const float* __restrict__ we,
                     float* __restrict__ ew){
  int t = blockIdx.x*256 + threadIdx.x;     // 32 blocks = 2*RR*128
  int lr = t >> 12;
  int rem = t & 4095;
  int r = rem >> 7, c = rem & 127;
  const float* W = we + (i64)lr*16384;
  float acc = 0.f;
  for (int k = 0; k < 128; k++) acc += rel[r*128 + k] * W[k*128 + c];
  ew[t] = acc;
}

// ---------------- MFMA GEMM kernels ----------------

// dense fp32-out: Y = xb @ W + bias
__global__ __launch_bounds__(256, 4) void k_mm_mfma(const ushort* __restrict__ xb,
    const ushort* __restrict__ wTb, const float* __restrict__ bias,
    float* __restrict__ Y, int nrows){
  __shared__ ushort Xs[16384];
  int t = threadIdx.x;
  int row0 = blockIdx.x * 128;
  for (int i = t; i < 2048; i += 256){
    int row = i >> 4, c = i & 15;
    int gr = min(row0 + row, nrows - 1);
    *(uint4*)((char*)Xs + row*256 + ((c*16) ^ ((row&7)<<4))) =
        *(const uint4*)((const char*)(xb + (i64)gr*128) + c*16);
  }
  __syncthreads();
  int w = t >> 6, l = t & 63;
  int wm = w >> 1, wn = w & 1;
  int lrow = l & 15, lg = l >> 4;
  int swz = (lrow & 7) << 4;
  const char* pX = (const char*)Xs + (wm*64 + lrow)*256;
  const char* pW = (const char*)wTb + (wn*64 + lrow)*256 + 16*lg;
  f32x4 acc[4][4] = {};
  #pragma unroll
  for (int ks = 0; ks < 4; ks++){
    int kb = (16*lg + 64*ks) ^ swz;
    bf16x8 a[4], bx[4];
    #pragma unroll
    for (int ns = 0; ns < 4; ns++) a[ns]  = *(const bf16x8*)(pW + ns*4096 + 64*ks);
    #pragma unroll
    for (int ms = 0; ms < 4; ms++) bx[ms] = *(const bf16x8*)(pX + ms*4096 + kb);
    #pragma unroll
    for (int ms = 0; ms < 4; ms++)
      #pragma unroll
      for (int ns = 0; ns < 4; ns++)
        acc[ms][ns] = __builtin_amdgcn_mfma_f32_16x16x32_bf16(a[ns], bx[ms], acc[ms][ns], 0, 0, 0);
  }
  #pragma unroll
  for (int ms = 0; ms < 4; ms++){
    int m = row0 + wm*64 + ms*16 + lrow;
    if (m >= nrows) continue;
    #pragma unroll
    for (int ns = 0; ns < 4; ns++){
      int n0 = wn*64 + ns*16 + 4*lg;
      float4 bv = *(const float4*)&bias[n0];
      f32x4 v = acc[ms][ns];
      *(float4*)&Y[(i64)m*128 + n0] =
          make_float4(v[0]+bv.x, v[1]+bv.y, v[2]+bv.z, v[3]+bv.w);
    }
  }
}

// fused q/k/v/skip: one X staging, 4 weight passes; q,k,v -> bf16, skip -> fp32
__global__ __launch_bounds__(256, 4) void k_mm4(const ushort* __restrict__ xb,
    const ushort* __restrict__ wTb, int layer,
    const float* __restrict__ biq, const float* __restrict__ bik,
    const float* __restrict__ biv, const float* __restrict__ bisk,
    ushort* __restrict__ qo, ushort* __restrict__ ko, ushort* __restrict__ vo,
    float* __restrict__ z, int nrows){
  __shared__ ushort Xs[16384];
  int t = threadIdx.x;
  int row0 = blockIdx.x * 128;
  for (int i = t; i < 2048; i += 256){
    int row = i >> 4, c = i & 15;
    int gr = min(row0 + row, nrows - 1);
    *(uint4*)((char*)Xs + row*256 + ((c*16) ^ ((row&7)<<4))) =
        *(const uint4*)((const char*)(xb + (i64)gr*128) + c*16);
  }
  __syncthreads();
  int w = t >> 6, l = t & 63;
  int wm = w >> 1, wn = w & 1;
  int lrow = l & 15, lg = l >> 4;
  int swz = (lrow & 7) << 4;
  const char* pX = (const char*)Xs + (wm*64 + lrow)*256;
  const float* biases[4] = {biq, bik, biv, bisk};
  ushort* outs[3] = {qo, ko, vo};
  #pragma unroll 1
  for (int arr = 0; arr < 4; arr++){
    const char* pW = (const char*)(wTb + (i64)(2 + 2*arr + layer)*16384)
                     + (wn*64 + lrow)*256 + 16*lg;
    f32x4 acc[4][4] = {};
    #pragma unroll
    for (int ks = 0; ks < 4; ks++){
      int kb = (16*lg + 64*ks) ^ swz;
      bf16x8 a[4], bx[4];
      #pragma unroll
      for (int ns = 0; ns < 4; ns++) a[ns]  = *(const bf16x8*)(pW + ns*4096 + 64*ks);
      #pragma unroll
      for (int ms = 0; ms < 4; ms++) bx[ms] = *(const bf16x8*)(pX + ms*4096 + kb);
      #pragma unroll
      for (int ms = 0; ms < 4; ms++)
        #pragma unroll
        for (int ns = 0; ns < 4; ns++)
          acc[ms][ns] = __builtin_amdgcn_mfma_f32_16x16x32_bf16(a[ns], bx[ms], acc[ms][ns], 0, 0, 0);
    }
    const float* bias = biases[arr];
    #pragma unroll
    for (int ms = 0; ms < 4; ms++){
      int m = row0 + wm*64 + ms*16 + lrow;
      if (m >= nrows) continue;
      #pragma unroll
      for (int ns = 0; ns < 4; ns++){
        int n0 = wn*64 + ns*16 + 4*lg;
        float4 bv = *(const float4*)&bias[n0];
        f32x4 v = acc[ms][ns];
        if (arr < 3){
          *(uint2*)&outs[arr][(i64)m*128 + n0] =
              make_uint2(pk2(v[0]+bv.x, v[1]+bv.y), pk2(v[2]+bv.z, v[3]+bv.w));
        } else {
          *(float4*)&z[(i64)m*128 + n0] =
              make_float4(v[0]+bv.x, v[1]+bv.y, v[2]+bv.z, v[3]+bv.w);
        }
      }
    }
  }
}

// edge: y[sg_p2[slot]][:] = sg_inv[slot] * (xb[sg_src[slot]] @ W[rel])
// bf16 out; output tile staged in LDS (Xs reuse) -> full-row coalesced writes.
__global__ __launch_bounds__(256, 4) void k_edge_mfma(
    const int* __restrict__ sg_src, const int* __restrict__ sg_p2,
    const float* __restrict__ sg_inv, const int* __restrict__ hist,
    const int* __restrict__ base, const int* __restrict__ pb,
    const ushort* __restrict__ xb, const ushort* __restrict__ wb,
    ushort* __restrict__ y){
  __shared__ ushort Xs[16384];
  __shared__ int s_src[128];
  __shared__ int s_p2[128];
  __shared__ float s_inv[128];
  int b = blockIdx.x;
  int r = -1;
  #pragma unroll 1
  for (int i = 0; i < RR; i++){
    if (b >= pb[i] && b < pb[i+1]) { r = i; break; }
  }
  if (r < 0) return;
  int chunk = b - pb[r];
  int rowbase = base[r] + chunk*128;
  int nvalid = min(128, hist[r] - chunk*128);
  int t = threadIdx.x;
  if (t < 128){
    bool valid = t < nvalid;
    int slot = rowbase + (valid ? t : 0);
    s_src[t] = sg_src[slot];
    s_p2[t]  = valid ? sg_p2[slot] : NE;     // NE = dump row
    s_inv[t] = valid ? sg_inv[slot] : 0.0f;
  }
  __syncthreads();
  for (int i = t; i < 2048; i += 256){
    int row = i >> 4, c = i & 15;
    *(uint4*)((char*)Xs + row*256 + ((c*16) ^ ((row&7)<<4))) =
        *(const uint4*)((const char*)(xb + (i64)s_src[row]*128) + c*16);
  }
  __syncthreads();
  int w = t >> 6, l = t & 63;
  int wm = w >> 1, wn = w & 1;
  int lrow = l & 15, lg = l >> 4;
  int swz = (lrow & 7) << 4;
  const char* pX = (const char*)Xs + (wm*64 + lrow)*256;
  const char* pW = (const char*)(wb + (i64)r*16384) + (wn*64 + lrow)*256 + 16*lg;
  f32x4 acc[4][4] = {};
  #pragma unroll
  for (int ks = 0; ks < 4; ks++){
    int kb = (16*lg + 64*ks) ^ swz;
    bf16x8 a[4], bx[4];
    #pragma unroll
    for (int ns = 0; ns < 4; ns++) a[ns]  = *(const bf16x8*)(pW + ns*4096 + 64*ks);
    #pragma unroll
    for (int ms = 0; ms < 4; ms++) bx[ms] = *(const bf16x8*)(pX + ms*4096 + kb);
    #pragma unroll
    for (int ms = 0; ms < 4; ms++)
      #pragma unroll
      for (int ns = 0; ns < 4; ns++)
        acc[ms][ns] = __builtin_amdgcn_mfma_f32_16x16x32_bf16(a[ns], bx[ms], acc[ms][ns], 0, 0, 0);
  }
  // stage scaled bf16 tile into Xs (X dead), swizzled like the input layout
  __syncthreads();
  #pragma unroll
  for (int ms = 0; ms < 4; ms++){
    int m = wm*64 + ms*16 + lrow;
    float sc = s_inv[m];
    int msk = (m & 7) << 4;
    #pragma unroll
    for (int ns = 0; ns < 4; ns++){
      int n0 = wn*64 + ns*16 + 4*lg;
      f32x4 v = acc[ms][ns];
      *(uint2*)((char*)Xs + m*256 + ((n0*2) ^ msk)) =
          make_uint2(pk2(v[0]*sc, v[1]*sc), pk2(v[2]*sc, v[3]*sc));
    }
  }
  __syncthreads();
  // coalesced full-row writes: 16 consecutive lanes emit one 256B y row
  for (int i = t; i < 2048; i += 256){
    int row = i >> 4, c = i & 15;
    uint4 v = *(const uint4*)((const char*)Xs + row*256 + ((c*16) ^ ((row&7)<<4)));
    *(uint4*)&y[(i64)s_p2[row]*128 + c*8] = v;
  }
}

// fallback (small ws): atomic scatter into z
__global__ __launch_bounds__(256) void k_edge_atomic(const int* __restrict__ esrc,
    const int* __restrict__ etgt, const int* __restrict__ eord,
    const int* __restrict__ hist, const int* __restrict__ base,
    const int* __restrict__ pb, const float* __restrict__ cnt,
    const float* __restrict__ x, const float* __restrict__ wT,
    float* __restrict__ z){
  __shared__ float Xs[64][132];
  __shared__ int s_src[64];
  __shared__ int s_tgt[64];
  __shared__ float s_inv[64];
  int b = blockIdx.x;
  int r = -1;
  #pragma unroll 1
  for (int i = 0; i < RR; i++){
    if (b >= pb[i] && b < pb[i+1]) { r = i; break; }
  }
  if (r < 0) return;
  int chunk = b - pb[r];
  int rowbase = base[r] + chunk*64;
  int cnt_r = hist[r];
  if (threadIdx.x < 64){
    int i = threadIdx.x;
    bool valid = (chunk*64 + i) < cnt_r;
    int eid = valid ? eord[rowbase + i] : 0;
    int sv = valid ? esrc[eid] : 0;
    int tv = valid ? etgt[eid] : 0;
    s_src[i] = sv; s_tgt[i] = tv;
    s_inv[i] = valid ? (1.0f / cnt[(i64)tv*RR + r]) : 0.0f;
  }
  __syncthreads();
  for (int idx = threadIdx.x; idx < 64*32; idx += 256){
    int rr = idx >> 5, c4 = idx & 31;
    *(float4*)&Xs[rr][c4*4] = ((const float4*)x)[(i64)s_src[rr]*32 + c4];
  }
  __syncthreads();
  const float* W = wT + (i64)r*16384;
  int m = threadIdx.x & 15, cg = threadIdx.x >> 4;
  float acc[4][8] = {};
  #pragma unroll 2
  for (int k4 = 0; k4 < 128; k4 += 4){
    float4 xv[4], wv[8];
    #pragma unroll
    for (int i = 0; i < 4; i++) xv[i] = *(float4*)&Xs[m + 16*i][k4];
    #pragma unroll
    for (int j = 0; j < 8; j++) wv[j] = *(const float4*)&W[(i64)(cg + 16*j)*128 + k4];
    #pragma unroll
    for (int i = 0; i < 4; i++)
      #pragma unroll
      for (int j = 0; j < 8; j++)
        acc[i][j] += xv[i].x*wv[j].x + xv[i].y*wv[j].y + xv[i].z*wv[j].z + xv[i].w*wv[j].w;
  }
  #pragma unroll
  for (int i = 0; i < 4; i++){
    int rr = m + 16*i;
    float sc = s_inv[rr];
    i64 o = (i64)s_tgt[rr]*128;
    #pragma unroll
    for (int j = 0; j < 8; j++)
      atomicAdd(&z[o + cg + 16*j], acc[i][j]*sc);
  }
}

// wave/target: x = relu(LN(z + sum y[q0..q1]))  (+ bf16 shadow), 2x unrolled stream
__global__ void k_seg(const int* __restrict__ rowptr, const ushort* __restrict__ y,
                      const float* __restrict__ z, const float* __restrict__ g,
                      const float* __restrict__ b, float* __restrict__ x,
                      ushort* __restrict__ xb){
  int t = (blockIdx.x*256 + threadIdx.x) >> 6;
  int l = threadIdx.x & 63;
  if (t >= NN) return;
  int q0 = rowptr[t], q1 = rowptr[t+1];
  float ax = 0.f, ay = 0.f;
  int q = q0;
  for (; q + 1 < q1; q += 2){
    ushort2 u0 = *(const ushort2*)&y[(i64)q*128 + 2*l];
    ushort2 u1 = *(const ushort2*)&y[(i64)(q+1)*128 + 2*l];
    ax += bf2f(u0.x) + bf2f(u1.x);
    ay += bf2f(u0.y) + bf2f(u1.y);
  }
  if (q < q1){
    ushort2 u = *(const ushort2*)&y[(i64)q*128 + 2*l];
    ax += bf2f(u.x); ay += bf2f(u.y);
  }
  float2 zv = *(const float2*)&z[(i64)t*128 + 2*l];
  float tx = ax + zv.x, ty = ay + zv.y;
  float s = tx + ty;
  #pragma unroll
  for (int o = 1; o < 64; o <<= 1) s += __shfl_xor(s, o);
  float mu = s * 0.0078125f;
  float dx = tx - mu, dy = ty - mu;
  float s2 = dx*dx + dy*dy;
  #pragma unroll
  for (int o = 1; o < 64; o <<= 1) s2 += __shfl_xor(s2, o);
  float rs = rsqrtf(s2 * 0.0078125f + 1e-5f);
  float2 gg = *(const float2*)&g[2*l];
  float2 bb = *(const float2*)&b[2*l];
  float o0 = fmaxf(dx*rs*gg.x + bb.x, 0.f);
  float o1 = fmaxf(dy*rs*gg.y + bb.y, 0.f);
  *(float2*)&x[(i64)t*128 + 2*l] = make_float2(o0, o1);
  *(unsigned*)&xb[(i64)t*128 + 2*l] = pk2(o0, o1);
}

// fallback LN
__global__ void k_lnrelu(const float* __restrict__ z, const float* __restrict__ g,
                         const float* __restrict__ b, float* __restrict__ xo,
                         ushort* __restrict__ xb){
  int w = (blockIdx.x*256 + threadIdx.x) >> 6;
  int l = threadIdx.x & 63;
  if (w >= NN) return;
  float2 v = *(const float2*)&z[(i64)w*128 + 2*l];
  float s = v.x + v.y;
  #pragma unroll
  for (int o = 1; o < 64; o <<= 1) s += __shfl_xor(s, o);
  float mu = s * 0.0078125f;
  float dx = v.x - mu, dy = v.y - mu;
  float s2 = dx*dx + dy*dy;
  #pragma unroll
  for (int o = 1; o < 64; o <<= 1) s2 += __shfl_xor(s2, o);
  float rs = rsqrtf(s2 * 0.0078125f + 1e-5f);
  float2 gg = *(const float2*)&g[2*l];
  float2 bb = *(const float2*)&b[2*l];
  float o0 = fmaxf(dx*rs*gg.x + bb.x, 0.f);
  float o1 = fmaxf(dy*rs*gg.y + bb.y, 0.f);
  *(float2*)&xo[(i64)w*128 + 2*l] = make_float2(o0, o1);
  *(unsigned*)&xb[(i64)w*128 + 2*l] = pk2(o0, o1);
}

// 1-wave-per-target attention (4 targets/block), no-max online sum,
// decoupled depth-4 prefetch; wave-local fused epilogue (no LDS exchange).
__global__ __launch_bounds__(256) void k_attn(const int2* __restrict__ se2,
    const int* __restrict__ rowptr,
    const ushort* __restrict__ qbb, const ushort* __restrict__ kbb,
    const ushort* __restrict__ vbb, const float* __restrict__ ew,
    const float* __restrict__ sk, const float* __restrict__ g,
    const float* __restrict__ b, const float* __restrict__ xin,
    float* __restrict__ xout, ushort* __restrict__ xb){
  __shared__ float sew[RR*128];
  for (int i = threadIdx.x; i < RR*32; i += 256)
    ((float4*)sew)[i] = ((const float4*)ew)[i];
  __syncthreads();
  int wid = threadIdx.x >> 6;
  int t = blockIdx.x*4 + wid;          // grid = NN/4 exactly
  int l = threadIdx.x & 63;
  int q0 = rowptr[t], q1 = rowptr[t+1];
  unsigned qu = *(const unsigned*)&qbb[(i64)t*128 + 2*l];
  float qx = bf2f((ushort)qu) * 0.25f, qy = bf2f((ushort)(qu >> 16)) * 0.25f;
  float den = 0.f, ox = 0.f, oy = 0.f;
  if (q0 < q1){
    // depth-4 pipeline; se2 padded with 8 zero entries at [NE..NE+7]
    int2 s0 = se2[q0], s1 = se2[q0+1], s2 = se2[q0+2], s3 = se2[q0+3];
    unsigned ku0 = *(const unsigned*)&kbb[(i64)s0.x*128 + 2*l];
    unsigned vu0 = *(const unsigned*)&vbb[(i64)s0.x*128 + 2*l];
    unsigned ku1 = *(const unsigned*)&kbb[(i64)s1.x*128 + 2*l];
    unsigned vu1 = *(const unsigned*)&vbb[(i64)s1.x*128 + 2*l];
    unsigned ku2 = *(const unsigned*)&kbb[(i64)s2.x*128 + 2*l];
    unsigned vu2 = *(const unsigned*)&vbb[(i64)s2.x*128 + 2*l];
    unsigned ku3 = *(const unsigned*)&kbb[(i64)s3.x*128 + 2*l];
    unsigned vu3 = *(const unsigned*)&vbb[(i64)s3.x*128 + 2*l];
    for (int q = q0; q < q1; q++){
      int2 s4 = se2[q + 4];
      unsigned ku4 = *(const unsigned*)&kbb[(i64)s4.x*128 + 2*l];
      unsigned vu4 = *(const unsigned*)&vbb[(i64)s4.x*128 + 2*l];
      float2 ev = *(const float2*)&sew[s0.y*128 + 2*l];
      float kx = bf2f((ushort)ku0) + ev.x, ky = bf2f((ushort)(ku0 >> 16)) + ev.y;
      float p = qx*kx + qy*ky;
      p += __shfl_xor(p, 1); p += __shfl_xor(p, 2); p += __shfl_xor(p, 4);
      float wgt = __expf(p);
      den += wgt;
      ox += wgt*(bf2f((ushort)vu0) + ev.x);
      oy += wgt*(bf2f((ushort)(vu0 >> 16)) + ev.y);
      s0 = s1; s1 = s2; s2 = s3; s3 = s4;
      ku0 = ku1; ku1 = ku2; ku2 = ku3; ku3 = ku4;
      vu0 = vu1; vu1 = vu2; vu2 = vu3; vu3 = vu4;
    }
  }
  float dn = fmaxf(den, 1e-16f);
  float2 zv = *(const float2*)&sk[(i64)t*128 + 2*l];
  float tx = ox/dn + zv.x, ty = oy/dn + zv.y;
  float s = tx + ty;
  #pragma unroll
  for (int o = 1; o < 64; o <<= 1) s += __shfl_xor(s, o);
  float mu = s * 0.0078125f;
  float dx = tx - mu, dy = ty - mu;
  float s2 = dx*dx + dy*dy;
  #pragma unroll
  for (int o = 1; o < 64; o <<= 1) s2 += __shfl_xor(s2, o);
  float rs = rsqrtf(s2 * 0.0078125f + 1e-5f);
  float2 gg = *(const float2*)&g[2*l];
  float2 bb = *(const float2*)&b[2*l];
  float o0 = fmaxf(dx*rs*gg.x + bb.x, 0.f);
  float o1 = fmaxf(dy*rs*gg.y + bb.y, 0.f);
  float2 xv = *(const float2*)&xin[(i64)t*128 + 2*l];
  float nx = xv.x + o0, ny = xv.y + o1;
  *(float2*)&xout[(i64)t*128 + 2*l] = make_float2(nx, ny);
  *(unsigned*)&xb[(i64)t*128 + 2*l] = pk2(nx, ny);
}

__global__ void k_pool(const float* __restrict__ x, const int* __restrict__ batch,
                       float* __restrict__ gsum){
  __shared__ float acc[NG*128];
  for (int i = threadIdx.x; i < NG*128; i += 256) acc[i] = 0.f;
  __syncthreads();
  int per = (NN + gridDim.x - 1) / gridDim.x;
  int n0 = blockIdx.x*per, n1 = min(n0 + per, NN);
  int sub = threadIdx.x >> 5, c4 = threadIdx.x & 31;
  for (int n = n0 + sub; n < n1; n += 8){
    int g = batch[n];
    float4 xv = ((const float4*)x)[(i64)n*32 + c4];
    atomicAdd(&acc[g*128 + c4*4 + 0], xv.x);
    atomicAdd(&acc[g*128 + c4*4 + 1], xv.y);
    atomicAdd(&acc[g*128 + c4*4 + 2], xv.z);
    atomicAdd(&acc[g*128 + c4*4 + 3], xv.w);
  }
  __syncthreads();
  for (int i = threadIdx.x; i < NG*128; i += 256) atomicAdd(&gsum[i], acc[i]);
}

__global__ void k_poolfin(const float* __restrict__ gsum, const float* __restrict__ cntg,
                          float* __restrict__ gout){
  int t = blockIdx.x*256 + threadIdx.x;
  int g = t >> 7;
  gout[t] = gsum[t] / fmaxf(cntg[g], 1.0f);
}

extern "C" void kernel_launch(void* const* d_in, const int* in_sizes, int n_in,
                              void* d_out, int out_size, void* d_ws, size_t ws_size,
                              hipStream_t stream) {
  const int*   node_ids = (const int*)d_in[0];
  const int*   eidx  = (const int*)d_in[1];
  const int*   esrc  = eidx;
  const int*   etgt  = eidx + NE;
  const int*   ety   = (const int*)d_in[2];
  const int*   batch = (const int*)d_in[3];
  const float* ent   = (const float*)d_in[4];
  const float* rel   = (const float*)d_in[5];
  const float* comp  = (const float*)d_in[6];
  const float* bases = (const float*)d_in[7];
  const float* root  = (const float*)d_in[8];
  const float* rbias = (const float*)d_in[9];
  const float* rlng  = (const float*)d_in[10];
  const float* rlnb  = (const float*)d_in[11];
  const float* wq    = (const float*)d_in[12];
  const float* bq    = (const float*)d_in[13];
  const float* wk    = (const float*)d_in[14];
  const float* bk    = (const float*)d_in[15];
  const float* wv    = (const float*)d_in[16];
  const float* bv    = (const float*)d_in[17];
  const float* we    = (const float*)d_in[18];
  const float* wsk   = (const float*)d_in[19];
  const float* bsk   = (const float*)d_in[20];
  const float* tlng  = (const float*)d_in[21];
  const float* tlnb  = (const float*)d_in[22];
  float* out = (float*)d_out;

  char* wp = (char*)d_ws;
  auto alloc = [&](size_t bytes)->void*{
    void* p = (void*)wp;
    wp += (bytes + 255) & ~(size_t)255;
    return p;
  };
  float*    x     = (float*)alloc((size_t)NN*128*4);
  ushort*   xb    = (ushort*)alloc((size_t)NN*128*2);
  float*    z     = (float*)alloc((size_t)NN*128*4);
  ushort*   qbb   = (ushort*)alloc((size_t)NN*128*2);
  ushort*   kbb   = (ushort*)alloc((size_t)NN*128*2);
  ushort*   vbb   = (ushort*)alloc((size_t)NN*128*2);
  float*    cnt   = (float*)alloc((size_t)NN*RR*4);
  float*    wbT   = (float*)alloc((size_t)2*RR*16384*4);
  ushort*   wbTb  = (ushort*)alloc((size_t)2*RR*16384*2);
  ushort*   wTb   = (ushort*)alloc((size_t)10*16384*2);
  float*    ew    = (float*)alloc((size_t)2*RR*128*4);
  int*      eord  = (int*)alloc((size_t)NE*4);
  int*      pos2  = (int*)alloc((size_t)NE*4);
  int2*     se2   = (int2*)alloc((size_t)(NE + 8)*8);
  int*      sg_src= (int*)alloc((size_t)NE*4);
  int*      sg_p2 = (int*)alloc((size_t)NE*4);
  float*    sg_inv= (float*)alloc((size_t)NE*4);
  int*      hist  = (int*)alloc(RR*4);
  int*      base  = (int*)alloc((RR+1)*4);
  int*      cursor= (int*)alloc(RR*4);
  int*      pb    = (int*)alloc((RR+1)*4);
  int*      pb64  = (int*)alloc((RR+1)*4);
  int*      hist2 = (int*)alloc((size_t)NN*4);
  int*      rowptr= (int*)alloc((size_t)(NN+1)*4);
  int*      cursor2=(int*)alloc((size_t)NN*4);
  float*    cntg  = (float*)alloc(NG*4);
  float*    gsum  = (float*)alloc((size_t)NG*128*4);
  size_t ybytes = (size_t)(NE + 8)*128*2;
  ushort*   y     = (ushort*)alloc(ybytes);
  bool fast = ((char*)y + ybytes) <= ((char*)d_ws + ws_size);

  dim3 B(256);

  hipMemsetAsync(cnt, 0, (size_t)NN*RR*4, stream);
  hipMemsetAsync(hist, 0, RR*4, stream);
  hipMemsetAsync(hist2, 0, (size_t)NN*4, stream);
  hipMemsetAsync(cntg, 0, NG*4, stream);

  k_gather<<<3750, B, 0, stream>>>(ent, node_ids, batch, x, xb, cntg);
  k_stats<<<294, B, 0, stream>>>(etgt, ety, cnt, hist, hist2);
  k_scan2<<<1, 1024, 0, stream>>>(hist2, rowptr, cursor2, hist, base, cursor, pb, pb64);
  k_scatter2<<<2344, B, 0, stream>>>(etgt, esrc, ety, cursor2, se2, pos2);
  k_scatter_blk<<<294, B, 0, stream>>>(ety, esrc, etgt, pos2, cnt, cursor, eord,
                                       sg_src, sg_p2, sg_inv);
  k_tw<<<dim3(64,10), B, 0, stream>>>(root, wq, wk, wv, wsk, wTb);
  k_basis<<<4096, B, 0, stream>>>(comp, bases, wbT, wbTb);
  k_ew<<<32, B, 0, stream>>>(rel, we, ew);

  for (int l = 0; l < 2; l++){
    k_mm_mfma<<<235, B, 0, stream>>>(xb, wTb + (i64)(0 + l)*16384, rbias + l*128, z, NN);
    if (fast){
      k_edge_mfma<<<4720, B, 0, stream>>>(sg_src, sg_p2, sg_inv, hist, base, pb,
                                          xb, wbTb + (i64)l*RR*16384, y);
      k_seg<<<7500, B, 0, stream>>>(rowptr, y, z, rlng + l*128, rlnb + l*128, x, xb);
    } else {
      k_edge_atomic<<<9407, B, 0, stream>>>(esrc, etgt, eord, hist, base, pb64, cnt,
                                            x, wbT + (i64)l*RR*16384, z);
      k_lnrelu<<<7500, B, 0, stream>>>(z, rlng + l*128, rlnb + l*128, x, xb);
    }
  }

  for (int l = 0; l < 2; l++){
    k_mm4<<<235, B, 0, stream>>>(xb, wTb, l, bq + l*128, bk + l*128, bv + l*128,
                                 bsk + l*128, qbb, kbb, vbb, z, NN);
    k_attn<<<7500, B, 0, stream>>>(se2, rowptr, qbb, kbb, vbb, ew + (i64)l*RR*128, z,
                                   tlng + l*128, tlnb + l*128, x,
                                   (l == 1) ? out : x, xb);
  }

  hipMemsetAsync(gsum, 0, (size_t)NG*128*4, stream);
  k_pool<<<120, B, 0, stream>>>(out, batch, gsum);
  k_poolfin<<<8, B, 0, stream>>>(gsum, cntg, out + (i64)NN*128);
}

// Round 12
// 774.884 us; speedup vs baseline: 1.1296x; 1.1296x over previous
//
#include <hip/hip_runtime.h>

#define NN 30000
#define NE 600000
#define RR 32
#define NBASE 30
#define NG 16

typedef long long i64;
typedef unsigned short ushort;
typedef short bf16x8 __attribute__((ext_vector_type(8)));
typedef float f32x4 __attribute__((ext_vector_type(4)));

__device__ __forceinline__ ushort f2bf(float f){
  unsigned u = __float_as_uint(f);
  u += 0x7fffu + ((u >> 16) & 1u);   // RNE
  return (ushort)(u >> 16);
}
__device__ __forceinline__ float bf2f(ushort u){
  return __uint_as_float(((unsigned)u) << 16);
}
__device__ __forceinline__ unsigned pk2(float a, float b){
  return (unsigned)f2bf(a) | ((unsigned)f2bf(b) << 16);
}

// x[n] = entity_emb[node_ids[n]] (fp32 + bf16 shadow) + per-graph node count
__global__ __launch_bounds__(256) void k_gather(const float* __restrict__ emb,
    const int* __restrict__ ids, const int* __restrict__ batch,
    float* __restrict__ x, ushort* __restrict__ xb, float* __restrict__ cntg){
  __shared__ int lh[NG];
  if (threadIdx.x < NG) lh[threadIdx.x] = 0;
  __syncthreads();
  int t = blockIdx.x*256 + threadIdx.x;       // grid 3750*256 == NN*32 exact
  int n = t >> 5, c = t & 31;
  float4 v = ((const float4*)emb)[(i64)ids[n]*32 + c];
  ((float4*)x)[(i64)n*32 + c] = v;
  *(uint2*)&xb[(i64)n*128 + c*4] = make_uint2(pk2(v.x, v.y), pk2(v.z, v.w));
  if (c == 0) atomicAdd(&lh[batch[n]], 1);
  __syncthreads();
  if (threadIdx.x < NG){
    int cv = lh[threadIdx.x];
    if (cv) atomicAdd(&cntg[threadIdx.x], (float)cv);
  }
}

// one pass over edges: relation hist (LDS-agg), target hist, (tgt,rel) counts
__global__ __launch_bounds__(256) void k_stats(const int* __restrict__ etgt,
    const int* __restrict__ ety, float* __restrict__ cnt,
    int* __restrict__ hist, int* __restrict__ hist2){
  __shared__ int lh[RR];
  if (threadIdx.x < RR) lh[threadIdx.x] = 0;
  __syncthreads();
  int e0 = blockIdx.x*2048 + threadIdx.x;
  #pragma unroll
  for (int i = 0; i < 8; i++){
    int e = e0 + i*256;
    if (e < NE){
      int tgt = etgt[e], r = ety[e];
      atomicAdd(&lh[r], 1);
      atomicAdd(&hist2[tgt], 1);
      atomicAdd(&cnt[(i64)tgt*RR + r], 1.0f);
    }
  }
  __syncthreads();
  if (threadIdx.x < RR){
    int v = lh[threadIdx.x];
    if (v) atomicAdd(&hist[threadIdx.x], v);
  }
}

// CSR scan over targets + (thread 0) relation scan
__global__ __launch_bounds__(1024) void k_scan2(const int* __restrict__ hist2,
    int* __restrict__ rowptr, int* __restrict__ cursor2,
    const int* __restrict__ hist, int* __restrict__ base,
    int* __restrict__ cursor, int* __restrict__ pb, int* __restrict__ pb64){
  int t = threadIdx.x;
  if (t == 0){
    int s = 0, p = 0, p64 = 0;
    for (int r = 0; r < RR; r++){
      base[r] = s; cursor[r] = s; pb[r] = p; pb64[r] = p64;
      s += hist[r]; p += (hist[r] + 127) >> 7; p64 += (hist[r] + 63) >> 6;
    }
    base[RR] = s; pb[RR] = p; pb64[RR] = p64;
  }
  __shared__ int s[1024];
  int bse = t*30;
  int loc[30];
  int sum = 0;
  #pragma unroll
  for (int i = 0; i < 30; i++){
    int v = (bse+i < NN) ? hist2[bse+i] : 0;
    loc[i] = sum; sum += v;
  }
  s[t] = sum; __syncthreads();
  for (int off = 1; off < 1024; off <<= 1){
    int v = (t >= off) ? s[t-off] : 0;
    __syncthreads();
    s[t] += v;
    __syncthreads();
  }
  int excl = (t > 0) ? s[t-1] : 0;
  #pragma unroll
  for (int i = 0; i < 30; i++){
    int idx = bse + i;
    if (idx <= NN){
      rowptr[idx] = excl + loc[i];
      if (idx < NN) cursor2[idx] = excl + loc[i];
    }
  }
}

// se2[q] = (src, rel) in CSR order; pos2: edge -> csr slot; 8 pad entries
__global__ void k_scatter2(const int* __restrict__ etgt, const int* __restrict__ esrc,
                           const int* __restrict__ ety, int* __restrict__ cursor2,
                           int2* __restrict__ se2, int* __restrict__ pos2){
  int e = blockIdx.x*256 + threadIdx.x;
  if (e >= NE) return;
  int q = atomicAdd(&cursor2[etgt[e]], 1);
  se2[q] = make_int2(esrc[e], ety[e]);
  pos2[e] = q;
  if (e < 8) se2[NE + e] = make_int2(0, 0);
}

// block-aggregated relation scatter; fused per-slot metadata (src, csr-slot, 1/cnt)
__global__ __launch_bounds__(256) void k_scatter_blk(const int* __restrict__ ety,
    const int* __restrict__ esrc, const int* __restrict__ etgt,
    const int* __restrict__ pos2, const float* __restrict__ cnt,
    int* __restrict__ cursor, int* __restrict__ eord,
    int* __restrict__ sg_src, int* __restrict__ sg_p2, float* __restrict__ sg_inv){
  __shared__ int lh[RR];
  __shared__ int lb[RR];
  if (threadIdx.x < RR) lh[threadIdx.x] = 0;
  __syncthreads();
  int e0 = blockIdx.x*2048 + threadIdx.x;
  #pragma unroll
  for (int i = 0; i < 8; i++){
    int e = e0 + i*256;
    if (e < NE) atomicAdd(&lh[ety[e]], 1);
  }
  __syncthreads();
  if (threadIdx.x < RR){
    int c = lh[threadIdx.x];
    lb[threadIdx.x] = c ? atomicAdd(&cursor[threadIdx.x], c) : 0;
  }
  __syncthreads();
  if (threadIdx.x < RR) lh[threadIdx.x] = 0;
  __syncthreads();
  #pragma unroll
  for (int i = 0; i < 8; i++){
    int e = e0 + i*256;
    if (e < NE){
      int r = ety[e];
      int loc = atomicAdd(&lh[r], 1);
      int slot = lb[r] + loc;
      eord[slot]   = e;
      sg_src[slot] = esrc[e];
      sg_p2[slot]  = pos2[e];
      sg_inv[slot] = 1.0f / cnt[(i64)etgt[e]*RR + r];
    }
  }
}

// LDS-tiled transpose of the 60 bases matrices: basesT[l][b][c][k] = bases[l][b][k][c]
__global__ __launch_bounds__(256) void k_tr(const float* __restrict__ in,
                                            float* __restrict__ out){
  __shared__ float tile[32][33];
  int m = blockIdx.y;                     // matrix 0..59
  int tb = blockIdx.x;                    // 0..15
  int row0 = (tb >> 2) * 32, col0 = (tb & 3) * 32;
  int tx = threadIdx.x & 31, ty = threadIdx.x >> 5;   // 32x8
  const float* src = in + (i64)m*16384;
  float* dst = out + (i64)m*16384;
  #pragma unroll
  for (int i = 0; i < 32; i += 8)
    tile[ty + i][tx] = src[(i64)(row0 + ty + i)*128 + col0 + tx];
  __syncthreads();
  #pragma unroll
  for (int i = 0; i < 32; i += 8)
    dst[(i64)(col0 + ty + i)*128 + row0 + tx] = tile[tx][ty + i];
}

// both layers, coalesced: wbT[l][r][ck] = sum_b comp[l][r][b]*basesT[l][b][ck]
__global__ void k_basis(const float* __restrict__ comp, const float* __restrict__ basesT,
                        float* __restrict__ wT, ushort* __restrict__ wTb){
  int t = blockIdx.x*256 + threadIdx.x;     // 4096 blocks = 2*RR*16384
  int lyr = t >> 19;
  int rem = t & 524287;
  int r = rem >> 14, ck = rem & 16383;
  const float* cp = comp + (i64)lyr*RR*NBASE + r*NBASE;
  const float* bs = basesT + (i64)lyr*NBASE*16384 + ck;
  float acc = 0.f;
  #pragma unroll 5
  for (int b = 0; b < NBASE; b++)
    acc += cp[b] * bs[(i64)b*16384];
  wT[t] = acc;
  wTb[t] = f2bf(acc);
}

// LDS-tiled transpose of dense weights -> bf16 [out][in]
__global__ __launch_bounds__(256) void k_tw(const float* __restrict__ root,
    const float* __restrict__ wq, const float* __restrict__ wk,
    const float* __restrict__ wv, const float* __restrict__ wsk,
    ushort* __restrict__ out){
  __shared__ float tile[32][33];
  int z = blockIdx.y;                     // 0..9
  const float* srcs[5] = {root, wq, wk, wv, wsk};
  const float* S = srcs[z >> 1] + (i64)(z & 1)*16384;
  int tb = blockIdx.x;                    // 0..15
  int row0 = (tb >> 2) * 32, col0 = (tb & 3) * 32;
  int tx = threadIdx.x & 31, ty = threadIdx.x >> 5;
  #pragma unroll
  for (int i = 0; i < 32; i += 8)
    tile[ty + i][tx] = S[(i64)(row0 + ty + i)*128 + col0 + tx];
  __syncthreads();
  ushort* dst = out + (i64)z*16384;
  #pragma unroll
  for (int i = 0; i < 32; i += 8)
    dst[(i64)(col0 + ty + i)*128 + row0 + tx] = f2bf(tile[tx][ty + i]);
}

// both layers: ew[l][r][c] = rel_emb[r] @ We[l]
__global__ void k_ew(const float* __restrict__ rel, const float* __restrict__ we,
                     float* __restrict__ ew){
  int t = blockIdx.x*256 + threadIdx.x;     // 32 blocks = 2*RR*128
  int lr = t >> 12;
  int rem = t & 4095;
  int r = rem >> 7, c = rem & 127;
  const float* W = we + (i64)lr*16384;
  float acc = 0.f;
  for (int k = 0; k < 128; k++) acc += rel[r*128 + k] * W[k*128 + c];
  ew[t] = acc;
}

// ---------------- MFMA GEMM kernels ----------------

// dense fp32-out: Y = xb @ W + bias
__global__ __launch_bounds__(256, 4) void k_mm_mfma(const ushort* __restrict__ xb,
    const ushort* __restrict__ wTb, const float* __restrict__ bias,
    float* __restrict__ Y, int nrows){
  __shared__ ushort Xs[16384];
  int t = threadIdx.x;
  int row0 = blockIdx.x * 128;
  for (int i = t; i < 2048; i += 256){
    int row = i >> 4, c = i & 15;
    int gr = min(row0 + row, nrows - 1);
    *(uint4*)((char*)Xs + row*256 + ((c*16) ^ ((row&7)<<4))) =
        *(const uint4*)((const char*)(xb + (i64)gr*128) + c*16);
  }
  __syncthreads();
  int w = t >> 6, l = t & 63;
  int wm = w >> 1, wn = w & 1;
  int lrow = l & 15, lg = l >> 4;
  int swz = (lrow & 7) << 4;
  const char* pX = (const char*)Xs + (wm*64 + lrow)*256;
  const char* pW = (const char*)wTb + (wn*64 + lrow)*256 + 16*lg;
  f32x4 acc[4][4] = {};
  #pragma unroll
  for (int ks = 0; ks < 4; ks++){
    int kb = (16*lg + 64*ks) ^ swz;
    bf16x8 a[4], bx[4];
    #pragma unroll
    for (int ns = 0; ns < 4; ns++) a[ns]  = *(const bf16x8*)(pW + ns*4096 + 64*ks);
    #pragma unroll
    for (int ms = 0; ms < 4; ms++) bx[ms] = *(const bf16x8*)(pX + ms*4096 + kb);
    #pragma unroll
    for (int ms = 0; ms < 4; ms++)
      #pragma unroll
      for (int ns = 0; ns < 4; ns++)
        acc[ms][ns] = __builtin_amdgcn_mfma_f32_16x16x32_bf16(a[ns], bx[ms], acc[ms][ns], 0, 0, 0);
  }
  #pragma unroll
  for (int ms = 0; ms < 4; ms++){
    int m = row0 + wm*64 + ms*16 + lrow;
    if (m >= nrows) continue;
    #pragma unroll
    for (int ns = 0; ns < 4; ns++){
      int n0 = wn*64 + ns*16 + 4*lg;
      float4 bv = *(const float4*)&bias[n0];
      f32x4 v = acc[ms][ns];
      *(float4*)&Y[(i64)m*128 + n0] =
          make_float4(v[0]+bv.x, v[1]+bv.y, v[2]+bv.z, v[3]+bv.w);
    }
  }
}

// fused q/k/v/skip: one X staging, 4 weight passes; q,k,v -> bf16, skip -> fp32
__global__ __launch_bounds__(256, 4) void k_mm4(const ushort* __restrict__ xb,
    const ushort* __restrict__ wTb, int layer,
    const float* __restrict__ biq, const float* __restrict__ bik,
    const float* __restrict__ biv, const float* __restrict__ bisk,
    ushort* __restrict__ qo, ushort* __restrict__ ko, ushort* __restrict__ vo,
    float* __restrict__ z, int nrows){
  __shared__ ushort Xs[16384];
  int t = threadIdx.x;
  int row0 = blockIdx.x * 128;
  for (int i = t; i < 2048; i += 256){
    int row = i >> 4, c = i & 15;
    int gr = min(row0 + row, nrows - 1);
    *(uint4*)((char*)Xs + row*256 + ((c*16) ^ ((row&7)<<4))) =
        *(const uint4*)((const char*)(xb + (i64)gr*128) + c*16);
  }
  __syncthreads();
  int w = t >> 6, l = t & 63;
  int wm = w >> 1, wn = w & 1;
  int lrow = l & 15, lg = l >> 4;
  int swz = (lrow & 7) << 4;
  const char* pX = (const char*)Xs + (wm*64 + lrow)*256;
  const float* biases[4] = {biq, bik, biv, bisk};
  ushort* outs[3] = {qo, ko, vo};
  #pragma unroll 1
  for (int arr = 0; arr < 4; arr++){
    const char* pW = (const char*)(wTb + (i64)(2 + 2*arr + layer)*16384)
                     + (wn*64 + lrow)*256 + 16*lg;
    f32x4 acc[4][4] = {};
    #pragma unroll
    for (int ks = 0; ks < 4; ks++){
      int kb = (16*lg + 64*ks) ^ swz;
      bf16x8 a[4], bx[4];
      #pragma unroll
      for (int ns = 0; ns < 4; ns++) a[ns]  = *(const bf16x8*)(pW + ns*4096 + 64*ks);
      #pragma unroll
      for (int ms = 0; ms < 4; ms++) bx[ms] = *(const bf16x8*)(pX + ms*4096 + kb);
      #pragma unroll
      for (int ms = 0; ms < 4; ms++)
        #pragma unroll
        for (int ns = 0; ns < 4; ns++)
          acc[ms][ns] = __builtin_amdgcn_mfma_f32_16x16x32_bf16(a[ns], bx[ms], acc[ms][ns], 0, 0, 0);
    }
    const float* bias = biases[arr];
    #pragma unroll
    for (int ms = 0; ms < 4; ms++){
      int m = row0 + wm*64 + ms*16 + lrow;
      if (m >= nrows) continue;
      #pragma unroll
      for (int ns = 0; ns < 4; ns++){
        int n0 = wn*64 + ns*16 + 4*lg;
        float4 bv = *(const float4*)&bias[n0];
        f32x4 v = acc[ms][ns];
        if (arr < 3){
          *(uint2*)&outs[arr][(i64)m*128 + n0] =
              make_uint2(pk2(v[0]+bv.x, v[1]+bv.y), pk2(v[2]+bv.z, v[3]+bv.w));
        } else {
          *(float4*)&z[(i64)m*128 + n0] =
              make_float4(v[0]+bv.x, v[1]+bv.y, v[2]+bv.z, v[3]+bv.w);
        }
      }
    }
  }
}

// edge: y[sg_p2[slot]][:] = sg_inv[slot] * (xb[sg_src[slot]] @ W[rel])
// bf16 out; output tile staged in LDS (Xs reuse) -> full-row coalesced writes.
__global__ __launch_bounds__(256, 4) void k_edge_mfma(
    const int* __restrict__ sg_src, const int* __restrict__ sg_p2,
    const float* __restrict__ sg_inv, const int* __restrict__ hist,
    const int* __restrict__ base, const int* __restrict__ pb,
    const ushort* __restrict__ xb, const ushort* __restrict__ wb,
    ushort* __restrict__ y){
  __shared__ ushort Xs[16384];
  __shared__ int s_src[128];
  __shared__ int s_p2[128];
  __shared__ float s_inv[128];
  int b = blockIdx.x;
  int r = -1;
  #pragma unroll 1
  for (int i = 0; i < RR; i++){
    if (b >= pb[i] && b < pb[i+1]) { r = i; break; }
  }
  if (r < 0) return;
  int chunk = b - pb[r];
  int rowbase = base[r] + chunk*128;
  int nvalid = min(128, hist[r] - chunk*128);
  int t = threadIdx.x;
  if (t < 128){
    bool valid = t < nvalid;
    int slot = rowbase + (valid ? t : 0);
    s_src[t] = sg_src[slot];
    s_p2[t]  = valid ? sg_p2[slot] : NE;     // NE = dump row
    s_inv[t] = valid ? sg_inv[slot] : 0.0f;
  }
  __syncthreads();
  for (int i = t; i < 2048; i += 256){
    int row = i >> 4, c = i & 15;
    *(uint4*)((char*)Xs + row*256 + ((c*16) ^ ((row&7)<<4))) =
        *(const uint4*)((const char*)(xb + (i64)s_src[row]*128) + c*16);
  }
  __syncthreads();
  int w = t >> 6, l = t & 63;
  int wm = w >> 1, wn = w & 1;
  int lrow = l & 15, lg = l >> 4;
  int swz = (lrow & 7) << 4;
  const char* pX = (const char*)Xs + (wm*64 + lrow)*256;
  const char* pW = (const char*)(wb + (i64)r*16384) + (wn*64 + lrow)*256 + 16*lg;
  f32x4 acc[4][4] = {};
  #pragma unroll
  for (int ks = 0; ks < 4; ks++){
    int kb = (16*lg + 64*ks) ^ swz;
    bf16x8 a[4], bx[4];
    #pragma unroll
    for (int ns = 0; ns < 4; ns++) a[ns]  = *(const bf16x8*)(pW + ns*4096 + 64*ks);
    #pragma unroll
    for (int ms = 0; ms < 4; ms++) bx[ms] = *(const bf16x8*)(pX + ms*4096 + kb);
    #pragma unroll
    for (int ms = 0; ms < 4; ms++)
      #pragma unroll
      for (int ns = 0; ns < 4; ns++)
        acc[ms][ns] = __builtin_amdgcn_mfma_f32_16x16x32_bf16(a[ns], bx[ms], acc[ms][ns], 0, 0, 0);
  }
  // stage scaled bf16 tile into Xs (X dead), swizzled like the input layout
  __syncthreads();
  #pragma unroll
  for (int ms = 0; ms < 4; ms++){
    int m = wm*64 + ms*16 + lrow;
    float sc = s_inv[m];
    int msk = (m & 7) << 4;
    #pragma unroll
    for (int ns = 0; ns < 4; ns++){
      int n0 = wn*64 + ns*16 + 4*lg;
      f32x4 v = acc[ms][ns];
      *(uint2*)((char*)Xs + m*256 + ((n0*2) ^ msk)) =
          make_uint2(pk2(v[0]*sc, v[1]*sc), pk2(v[2]*sc, v[3]*sc));
    }
  }
  __syncthreads();
  // coalesced full-row writes: 16 consecutive lanes emit one 256B y row
  for (int i = t; i < 2048; i += 256){
    int row = i >> 4, c = i & 15;
    uint4 v = *(const uint4*)((const char*)Xs + row*256 + ((c*16) ^ ((row&7)<<4)));
    *(uint4*)&y[(i64)s_p2[row]*128 + c*8] = v;
  }
}

// fallback (small ws): atomic scatter into z
__global__ __launch_bounds__(256) void k_edge_atomic(const int* __restrict__ esrc,
    const int* __restrict__ etgt, const int* __restrict__ eord,
    const int* __restrict__ hist, const int* __restrict__ base,
    const int* __restrict__ pb, const float* __restrict__ cnt,
    const float* __restrict__ x, const float* __restrict__ wT,
    float* __restrict__ z){
  __shared__ float Xs[64][132];
  __shared__ int s_src[64];
  __shared__ int s_tgt[64];
  __shared__ float s_inv[64];
  int b = blockIdx.x;
  int r = -1;
  #pragma unroll 1
  for (int i = 0; i < RR; i++){
    if (b >= pb[i] && b < pb[i+1]) { r = i; break; }
  }
  if (r < 0) return;
  int chunk = b - pb[r];
  int rowbase = base[r] + chunk*64;
  int cnt_r = hist[r];
  if (threadIdx.x < 64){
    int i = threadIdx.x;
    bool valid = (chunk*64 + i) < cnt_r;
    int eid = valid ? eord[rowbase + i] : 0;
    int sv = valid ? esrc[eid] : 0;
    int tv = valid ? etgt[eid] : 0;
    s_src[i] = sv; s_tgt[i] = tv;
    s_inv[i] = valid ? (1.0f / cnt[(i64)tv*RR + r]) : 0.0f;
  }
  __syncthreads();
  for (int idx = threadIdx.x; idx < 64*32; idx += 256){
    int rr = idx >> 5, c4 = idx & 31;
    *(float4*)&Xs[rr][c4*4] = ((const float4*)x)[(i64)s_src[rr]*32 + c4];
  }
  __syncthreads();
  const float* W = wT + (i64)r*16384;
  int m = threadIdx.x & 15, cg = threadIdx.x >> 4;
  float acc[4][8] = {};
  #pragma unroll 2
  for (int k4 = 0; k4 < 128; k4 += 4){
    float4 xv[4], wv[8];
    #pragma unroll
    for (int i = 0; i < 4; i++) xv[i] = *(float4*)&Xs[m + 16*i][k4];
    #pragma unroll
    for (int j = 0; j < 8; j++) wv[j] = *(const float4*)&W[(i64)(cg + 16*j)*128 + k4];
    #pragma unroll
    for (int i = 0; i < 4; i++)
      #pragma unroll
      for (int j = 0; j < 8; j++)
        acc[i][j] += xv[i].x*wv[j].x + xv[i].y*wv[j].y + xv[i].z*wv[j].z + xv[i].w*wv[j].w;
  }
  #pragma unroll
  for (int i = 0; i < 4; i++){
    int rr = m + 16*i;
    float sc = s_inv[rr];
    i64 o = (i64)s_tgt[rr]*128;
    #pragma unroll
    for (int j = 0; j < 8; j++)
      atomicAdd(&z[o + cg + 16*j], acc[i][j]*sc);
  }
}

// wave/target: x = relu(LN(z + sum y[q0..q1]))  (+ bf16 shadow), 2x unrolled stream
__global__ void k_seg(const int* __restrict__ rowptr, const ushort* __restrict__ y,
                      const float* __restrict__ z, const float* __restrict__ g,
                      const float* __restrict__ b, float* __restrict__ x,
                      ushort* __restrict__ xb){
  int t = (blockIdx.x*256 + threadIdx.x) >> 6;
  int l = threadIdx.x & 63;
  if (t >= NN) return;
  int q0 = rowptr[t], q1 = rowptr[t+1];
  float ax = 0.f, ay = 0.f;
  int q = q0;
  for (; q + 1 < q1; q += 2){
    ushort2 u0 = *(const ushort2*)&y[(i64)q*128 + 2*l];
    ushort2 u1 = *(const ushort2*)&y[(i64)(q+1)*128 + 2*l];
    ax += bf2f(u0.x) + bf2f(u1.x);
    ay += bf2f(u0.y) + bf2f(u1.y);
  }
  if (q < q1){
    ushort2 u = *(const ushort2*)&y[(i64)q*128 + 2*l];
    ax += bf2f(u.x); ay += bf2f(u.y);
  }
  float2 zv = *(const float2*)&z[(i64)t*128 + 2*l];
  float tx = ax + zv.x, ty = ay + zv.y;
  float s = tx + ty;
  #pragma unroll
  for (int o = 1; o < 64; o <<= 1) s += __shfl_xor(s, o);
  float mu = s * 0.0078125f;
  float dx = tx - mu, dy = ty - mu;
  float s2 = dx*dx + dy*dy;
  #pragma unroll
  for (int o = 1; o < 64; o <<= 1) s2 += __shfl_xor(s2, o);
  float rs = rsqrtf(s2 * 0.0078125f + 1e-5f);
  float2 gg = *(const float2*)&g[2*l];
  float2 bb = *(const float2*)&b[2*l];
  float o0 = fmaxf(dx*rs*gg.x + bb.x, 0.f);
  float o1 = fmaxf(dy*rs*gg.y + bb.y, 0.f);
  *(float2*)&x[(i64)t*128 + 2*l] = make_float2(o0, o1);
  *(unsigned*)&xb[(i64)t*128 + 2*l] = pk2(o0, o1);
}

// fallback LN
__global__ void k_lnrelu(const float* __restrict__ z, const float* __restrict__ g,
                         const float* __restrict__ b, float* __restrict__ xo,
                         ushort* __restrict__ xb){
  int w = (blockIdx.x*256 + threadIdx.x) >> 6;
  int l = threadIdx.x & 63;
  if (w >= NN) return;
  float2 v = *(const float2*)&z[(i64)w*128 + 2*l];
  float s = v.x + v.y;
  #pragma unroll
  for (int o = 1; o < 64; o <<= 1) s += __shfl_xor(s, o);
  float mu = s * 0.0078125f;
  float dx = v.x - mu, dy = v.y - mu;
  float s2 = dx*dx + dy*dy;
  #pragma unroll
  for (int o = 1; o < 64; o <<= 1) s2 += __shfl_xor(s2, o);
  float rs = rsqrtf(s2 * 0.0078125f + 1e-5f);
  float2 gg = *(const float2*)&g[2*l];
  float2 bb = *(const float2*)&b[2*l];
  float o0 = fmaxf(dx*rs*gg.x + bb.x, 0.f);
  float o1 = fmaxf(dy*rs*gg.y + bb.y, 0.f);
  *(float2*)&xo[(i64)w*128 + 2*l] = make_float2(o0, o1);
  *(unsigned*)&xb[(i64)w*128 + 2*l] = pk2(o0, o1);
}

// 1-wave-per-target attention (4 targets/block), no-max online sum,
// decoupled depth-4 prefetch; wave-local fused epilogue (no LDS exchange).
__global__ __launch_bounds__(256) void k_attn(const int2* __restrict__ se2,
    const int* __restrict__ rowptr,
    const ushort* __restrict__ qbb, const ushort* __restrict__ kbb,
    const ushort* __restrict__ vbb, const float* __restrict__ ew,
    const float* __restrict__ sk, const float* __restrict__ g,
    const float* __restrict__ b, const float* __restrict__ xin,
    float* __restrict__ xout, ushort* __restrict__ xb){
  __shared__ float sew[RR*128];
  for (int i = threadIdx.x; i < RR*32; i += 256)
    ((float4*)sew)[i] = ((const float4*)ew)[i];
  __syncthreads();
  int wid = threadIdx.x >> 6;
  int t = blockIdx.x*4 + wid;          // grid = NN/4 exactly
  int l = threadIdx.x & 63;
  int q0 = rowptr[t], q1 = rowptr[t+1];
  unsigned qu = *(const unsigned*)&qbb[(i64)t*128 + 2*l];
  float qx = bf2f((ushort)qu) * 0.25f, qy = bf2f((ushort)(qu >> 16)) * 0.25f;
  float den = 0.f, ox = 0.f, oy = 0.f;
  if (q0 < q1){
    // depth-4 pipeline; se2 padded with 8 zero entries at [NE..NE+7]
    int2 s0 = se2[q0], s1 = se2[q0+1], s2 = se2[q0+2], s3 = se2[q0+3];
    unsigned ku0 = *(const unsigned*)&kbb[(i64)s0.x*128 + 2*l];
    unsigned vu0 = *(const unsigned*)&vbb[(i64)s0.x*128 + 2*l];
    unsigned ku1 = *(const unsigned*)&kbb[(i64)s1.x*128 + 2*l];
    unsigned vu1 = *(const unsigned*)&vbb[(i64)s1.x*128 + 2*l];
    unsigned ku2 = *(const unsigned*)&kbb[(i64)s2.x*128 + 2*l];
    unsigned vu2 = *(const unsigned*)&vbb[(i64)s2.x*128 + 2*l];
    unsigned ku3 = *(const unsigned*)&kbb[(i64)s3.x*128 + 2*l];
    unsigned vu3 = *(const unsigned*)&vbb[(i64)s3.x*128 + 2*l];
    for (int q = q0; q < q1; q++){
      int2 s4 = se2[q + 4];
      unsigned ku4 = *(const unsigned*)&kbb[(i64)s4.x*128 + 2*l];
      unsigned vu4 = *(const unsigned*)&vbb[(i64)s4.x*128 + 2*l];
      float2 ev = *(const float2*)&sew[s0.y*128 + 2*l];
      float kx = bf2f((ushort)ku0) + ev.x, ky = bf2f((ushort)(ku0 >> 16)) + ev.y;
      float p = qx*kx + qy*ky;
      p += __shfl_xor(p, 1); p += __shfl_xor(p, 2); p += __shfl_xor(p, 4);
      float wgt = __expf(p);
      den += wgt;
      ox += wgt*(bf2f((ushort)vu0) + ev.x);
      oy += wgt*(bf2f((ushort)(vu0 >> 16)) + ev.y);
      s0 = s1; s1 = s2; s2 = s3; s3 = s4;
      ku0 = ku1; ku1 = ku2; ku2 = ku3; ku3 = ku4;
      vu0 = vu1; vu1 = vu2; vu2 = vu3; vu3 = vu4;
    }
  }
  float dn = fmaxf(den, 1e-16f);
  float2 zv = *(const float2*)&sk[(i64)t*128 + 2*l];
  float tx = ox/dn + zv.x, ty = oy/dn + zv.y;
  float s = tx + ty;
  #pragma unroll
  for (int o = 1; o < 64; o <<= 1) s += __shfl_xor(s, o);
  float mu = s * 0.0078125f;
  float dx = tx - mu, dy = ty - mu;
  float s2 = dx*dx + dy*dy;
  #pragma unroll
  for (int o = 1; o < 64; o <<= 1) s2 += __shfl_xor(s2, o);
  float rs = rsqrtf(s2 * 0.0078125f + 1e-5f);
  float2 gg = *(const float2*)&g[2*l];
  float2 bb = *(const float2*)&b[2*l];
  float o0 = fmaxf(dx*rs*gg.x + bb.x, 0.f);
  float o1 = fmaxf(dy*rs*gg.y + bb.y, 0.f);
  float2 xv = *(const float2*)&xin[(i64)t*128 + 2*l];
  float nx = xv.x + o0, ny = xv.y + o1;
  *(float2*)&xout[(i64)t*128 + 2*l] = make_float2(nx, ny);
  *(unsigned*)&xb[(i64)t*128 + 2*l] = pk2(nx, ny);
}

__global__ void k_pool(const float* __restrict__ x, const int* __restrict__ batch,
                       float* __restrict__ gsum){
  __shared__ float acc[NG*128];
  for (int i = threadIdx.x; i < NG*128; i += 256) acc[i] = 0.f;
  __syncthreads();
  int per = (NN + gridDim.x - 1) / gridDim.x;
  int n0 = blockIdx.x*per, n1 = min(n0 + per, NN);
  int sub = threadIdx.x >> 5, c4 = threadIdx.x & 31;
  for (int n = n0 + sub; n < n1; n += 8){
    int g = batch[n];
    float4 xv = ((const float4*)x)[(i64)n*32 + c4];
    atomicAdd(&acc[g*128 + c4*4 + 0], xv.x);
    atomicAdd(&acc[g*128 + c4*4 + 1], xv.y);
    atomicAdd(&acc[g*128 + c4*4 + 2], xv.z);
    atomicAdd(&acc[g*128 + c4*4 + 3], xv.w);
  }
  __syncthreads();
  for (int i = threadIdx.x; i < NG*128; i += 256) atomicAdd(&gsum[i], acc[i]);
}

__global__ void k_poolfin(const float* __restrict__ gsum, const float* __restrict__ cntg,
                          float* __restrict__ gout){
  int t = blockIdx.x*256 + threadIdx.x;
  int g = t >> 7;
  gout[t] = gsum[t] / fmaxf(cntg[g], 1.0f);
}

extern "C" void kernel_launch(void* const* d_in, const int* in_sizes, int n_in,
                              void* d_out, int out_size, void* d_ws, size_t ws_size,
                              hipStream_t stream) {
  const int*   node_ids = (const int*)d_in[0];
  const int*   eidx  = (const int*)d_in[1];
  const int*   esrc  = eidx;
  const int*   etgt  = eidx + NE;
  const int*   ety   = (const int*)d_in[2];
  const int*   batch = (const int*)d_in[3];
  const float* ent   = (const float*)d_in[4];
  const float* rel   = (const float*)d_in[5];
  const float* comp  = (const float*)d_in[6];
  const float* bases = (const float*)d_in[7];
  const float* root  = (const float*)d_in[8];
  const float* rbias = (const float*)d_in[9];
  const float* rlng  = (const float*)d_in[10];
  const float* rlnb  = (const float*)d_in[11];
  const float* wq    = (const float*)d_in[12];
  const float* bq    = (const float*)d_in[13];
  const float* wk    = (const float*)d_in[14];
  const float* bk    = (const float*)d_in[15];
  const float* wv    = (const float*)d_in[16];
  const float* bv    = (const float*)d_in[17];
  const float* we    = (const float*)d_in[18];
  const float* wsk   = (const float*)d_in[19];
  const float* bsk   = (const float*)d_in[20];
  const float* tlng  = (const float*)d_in[21];
  const float* tlnb  = (const float*)d_in[22];
  float* out = (float*)d_out;

  char* wp = (char*)d_ws;
  auto alloc = [&](size_t bytes)->void*{
    void* p = (void*)wp;
    wp += (bytes + 255) & ~(size_t)255;
    return p;
  };
  float*    x     = (float*)alloc((size_t)NN*128*4);
  ushort*   xb    = (ushort*)alloc((size_t)NN*128*2);
  float*    z     = (float*)alloc((size_t)NN*128*4);
  ushort*   qbb   = (ushort*)alloc((size_t)NN*128*2);
  ushort*   kbb   = (ushort*)alloc((size_t)NN*128*2);
  ushort*   vbb   = (ushort*)alloc((size_t)NN*128*2);
  float*    cnt   = (float*)alloc((size_t)NN*RR*4);
  float*    basesT= (float*)alloc((size_t)2*NBASE*16384*4);
  float*    wbT   = (float*)alloc((size_t)2*RR*16384*4);
  ushort*   wbTb  = (ushort*)alloc((size_t)2*RR*16384*2);
  ushort*   wTb   = (ushort*)alloc((size_t)10*16384*2);
  float*    ew    = (float*)alloc((size_t)2*RR*128*4);
  int*      eord  = (int*)alloc((size_t)NE*4);
  int*      pos2  = (int*)alloc((size_t)NE*4);
  int2*     se2   = (int2*)alloc((size_t)(NE + 8)*8);
  int*      sg_src= (int*)alloc((size_t)NE*4);
  int*      sg_p2 = (int*)alloc((size_t)NE*4);
  float*    sg_inv= (float*)alloc((size_t)NE*4);
  int*      hist  = (int*)alloc(RR*4);
  int*      base  = (int*)alloc((RR+1)*4);
  int*      cursor= (int*)alloc(RR*4);
  int*      pb    = (int*)alloc((RR+1)*4);
  int*      pb64  = (int*)alloc((RR+1)*4);
  int*      hist2 = (int*)alloc((size_t)NN*4);
  int*      rowptr= (int*)alloc((size_t)(NN+1)*4);
  int*      cursor2=(int*)alloc((size_t)NN*4);
  float*    cntg  = (float*)alloc(NG*4);
  float*    gsum  = (float*)alloc((size_t)NG*128*4);
  size_t ybytes = (size_t)(NE + 8)*128*2;
  ushort*   y     = (ushort*)alloc(ybytes);
  bool fast = ((char*)y + ybytes) <= ((char*)d_ws + ws_size);

  dim3 B(256);

  hipMemsetAsync(cnt, 0, (size_t)NN*RR*4, stream);
  hipMemsetAsync(hist, 0, RR*4, stream);
  hipMemsetAsync(hist2, 0, (size_t)NN*4, stream);
  hipMemsetAsync(cntg, 0, NG*4, stream);

  k_gather<<<3750, B, 0, stream>>>(ent, node_ids, batch, x, xb, cntg);
  k_stats<<<294, B, 0, stream>>>(etgt, ety, cnt, hist, hist2);
  k_scan2<<<1, 1024, 0, stream>>>(hist2, rowptr, cursor2, hist, base, cursor, pb, pb64);
  k_scatter2<<<2344, B, 0, stream>>>(etgt, esrc, ety, cursor2, se2, pos2);
  k_scatter_blk<<<294, B, 0, stream>>>(ety, esrc, etgt, pos2, cnt, cursor, eord,
                                       sg_src, sg_p2, sg_inv);
  k_tr<<<dim3(16, 60), B, 0, stream>>>(bases, basesT);
  k_tw<<<dim3(16, 10), B, 0, stream>>>(root, wq, wk, wv, wsk, wTb);
  k_basis<<<4096, B, 0, stream>>>(comp, basesT, wbT, wbTb);
  k_ew<<<32, B, 0, stream>>>(rel, we, ew);

  for (int l = 0; l < 2; l++){
    k_mm_mfma<<<235, B, 0, stream>>>(xb, wTb + (i64)(0 + l)*16384, rbias + l*128, z, NN);
    if (fast){
      k_edge_mfma<<<4720, B, 0, stream>>>(sg_src, sg_p2, sg_inv, hist, base, pb,
                                          xb, wbTb + (i64)l*RR*16384, y);
      k_seg<<<7500, B, 0, stream>>>(rowptr, y, z, rlng + l*128, rlnb + l*128, x, xb);
    } else {
      k_edge_atomic<<<9407, B, 0, stream>>>(esrc, etgt, eord, hist, base, pb64, cnt,
                                            x, wbT + (i64)l*RR*16384, z);
      k_lnrelu<<<7500, B, 0, stream>>>(z, rlng + l*128, rlnb + l*128, x, xb);
    }
  }

  for (int l = 0; l < 2; l++){
    k_mm4<<<235, B, 0, stream>>>(xb, wTb, l, bq + l*128, bk + l*128, bv + l*128,
                                 bsk + l*128, qbb, kbb, vbb, z, NN);
    k_attn<<<7500, B, 0, stream>>>(se2, rowptr, qbb, kbb, vbb, ew + (i64)l*RR*128, z,
                                   tlng + l*128, tlnb + l*128, x,
                                   (l == 1) ? out : x, xb);
  }

  hipMemsetAsync(gsum, 0, (size_t)NG*128*4, stream);
  k_pool<<<120, B, 0, stream>>>(out, batch, gsum);
  k_poolfin<<<8, B, 0, stream>>>(gsum, cntg, out + (i64)NN*128);
}